// Round 2
// baseline (165.764 us; speedup 1.0000x reference)
//
#include <hip/hip_runtime.h>

// Problem constants (fixed by the reference): B=64, D=2048, UNITS=1024, NW=64.
// L (bucket capacity) is runtime-derived: in_sizes[3] / (UNITS*NW).
//
// out[b,u] = sum_i x[b,i] * W[u,i] + bias[u], where W[u,i] = w[k] iff
// indices[u,k,l] == i+1 for some l. Buckets partition positions per unit, so
// scattering w[k] into a zero-initialized LDS row builds W[u,:] race-free.
//
// R2 changes vs R1 (theory-first):
//  - Phase 1: explicit (uu,k) pair ownership -> zero runtime int divisions
//    (was 2 divs x 28 iters/thread, ~1400 VALU insts).
//  - Phase 2: float4 x loads + ds_read_b128 row reads (4x fewer mem insts).
//  - 1024 threads/block: 16 waves/CU (50% occ) instead of 8 (25%).

#define B_DIM   64
#define D_DIM   2048
#define D4      (D_DIM / 4)     // 512 float4 per row
#define UNITS_N 1024
#define NW_N    64
#define U_PER_BLOCK 4
#define THREADS 1024

__global__ __launch_bounds__(THREADS)
void EfficientHashedLinear_72043781423546_kernel(
    const float* __restrict__ x,        // (64, 2048)
    const float* __restrict__ w,        // (64,)
    const float* __restrict__ bias,     // (1024,)
    const int*   __restrict__ indices,  // (UNITS, NW, L) int32, 1-shifted, 0 = pad
    float*       __restrict__ out,      // (64, 1024)
    int L)
{
    __shared__ float rows[U_PER_BLOCK][D_DIM];   // 32 KB: W[u0+uu, :]
    __shared__ float w_lds[NW_N];

    const int tid  = threadIdx.x;
    const int wave = tid >> 6;          // 0..15
    const int lane = tid & 63;
    const int u0   = blockIdx.x * U_PER_BLOCK;

    // Phase 0: zero the weight rows (float4 stores), stage w.
    {
        float4* r4 = (float4*)rows;
        const float4 z = make_float4(0.f, 0.f, 0.f, 0.f);
        #pragma unroll
        for (int i = tid; i < U_PER_BLOCK * D4; i += THREADS)
            r4[i] = z;
        if (tid < NW_N) w_lds[tid] = w[tid];
    }
    __syncthreads();

    // Phase 1: scatter. 256 (uu,k) pairs over 16 waves -> 16 pairs/wave.
    // Lane l reads bucket entry l (coalesced, contiguous per bucket).
    // No divisions: uu = pair>>6, k = pair&63.
    #pragma unroll 4
    for (int p = 0; p < 16; ++p) {
        const int pair = wave * 16 + p;           // 0..255
        const int uu   = pair >> 6;               // 0..3
        const int k    = pair & 63;               // 0..63
        const int* bp  = indices + ((size_t)(u0 + uu) * NW_N + k) * L;
        const float wk = w_lds[k];                // wave-uniform broadcast
        for (int l = lane; l < L; l += 64) {
            int idx = bp[l];
            if (idx > 0) rows[uu][idx - 1] = wk;
        }
    }
    __syncthreads();

    // Phase 2: each wave owns 4 batch rows; lanes split D as float4.
    const int b0 = wave * 4;                      // 16 waves x 4 = 64 rows
    const float4* x4 = (const float4*)x;

    float acc[4][U_PER_BLOCK];
    #pragma unroll
    for (int bj = 0; bj < 4; ++bj)
        #pragma unroll
        for (int uu = 0; uu < U_PER_BLOCK; ++uu)
            acc[bj][uu] = 0.0f;

    #pragma unroll
    for (int step = 0; step < D4 / 64; ++step) {  // 8 steps
        const int i4 = step * 64 + lane;          // 0..511
        float4 rv[U_PER_BLOCK];
        #pragma unroll
        for (int uu = 0; uu < U_PER_BLOCK; ++uu)
            rv[uu] = ((const float4*)rows[uu])[i4];   // ds_read_b128
        #pragma unroll
        for (int bj = 0; bj < 4; ++bj) {
            const float4 xv = x4[(b0 + bj) * D4 + i4];
            #pragma unroll
            for (int uu = 0; uu < U_PER_BLOCK; ++uu) {
                acc[bj][uu] += xv.x * rv[uu].x;
                acc[bj][uu] += xv.y * rv[uu].y;
                acc[bj][uu] += xv.z * rv[uu].z;
                acc[bj][uu] += xv.w * rv[uu].w;
            }
        }
    }

    // Phase 3: 64-lane butterfly reduce, add bias, store (16 outputs/wave).
    #pragma unroll
    for (int bj = 0; bj < 4; ++bj) {
        #pragma unroll
        for (int uu = 0; uu < U_PER_BLOCK; ++uu) {
            float v = acc[bj][uu];
            #pragma unroll
            for (int off = 32; off > 0; off >>= 1)
                v += __shfl_down(v, off, 64);
            if (lane == 0)
                out[(b0 + bj) * UNITS_N + (u0 + uu)] = v + bias[u0 + uu];
        }
    }
}

extern "C" void kernel_launch(void* const* d_in, const int* in_sizes, int n_in,
                              void* d_out, int out_size, void* d_ws, size_t ws_size,
                              hipStream_t stream) {
    const float* x       = (const float*)d_in[0];
    const float* w       = (const float*)d_in[1];
    const float* bias    = (const float*)d_in[2];
    const int*   indices = (const int*)d_in[3];
    float*       out     = (float*)d_out;

    const int L = in_sizes[3] / (UNITS_N * NW_N);

    dim3 grid(UNITS_N / U_PER_BLOCK);   // 256 blocks = 1 per CU
    dim3 block(THREADS);                // 1024 threads = 16 waves
    EfficientHashedLinear_72043781423546_kernel<<<grid, block, 0, stream>>>(
        x, w, bias, indices, out, L);
}

// Round 3
// 102.954 us; speedup vs baseline: 1.6101x; 1.6101x over previous
//
#include <hip/hip_runtime.h>

// B=64, D=2048, UNITS=1024, NW=64; L = in_sizes[3]/(UNITS*NW) (~56).
//
// out[b,u] = sum_i x[b,i] * W[u,i] + bias[u], W[u,i] = w[k] where bucket k of
// unit u contains position i (indices are 1-shifted, 0 = pad). Buckets
// partition positions per unit -> LDS scatter builds W[u,:] race-free.
//
// R3 vs R2 post-mortem: R2's 1024-thread __launch_bounds__ forced a 64-VGPR
// cap; full unroll of the step loop then spilled ~590 B/thread to scratch
// (WRITE_SIZE 154 MB, FETCH 208 MB, VALUBusy 5.5%). R3: 512 threads,
// unroll 1 on the step loop (live set ~90 VGPRs), same vectorization.

#define B_DIM   64
#define D_DIM   2048
#define D4      (D_DIM / 4)     // 512 float4 per row
#define UNITS_N 1024
#define NW_N    64
#define U_PER_BLOCK 4
#define THREADS 512

__global__ __launch_bounds__(THREADS)
void EfficientHashedLinear_72043781423546_kernel(
    const float* __restrict__ x,        // (64, 2048)
    const float* __restrict__ w,        // (64,)
    const float* __restrict__ bias,     // (1024,)
    const int*   __restrict__ indices,  // (UNITS, NW, L) int32
    float*       __restrict__ out,      // (64, 1024)
    int L)
{
    __shared__ float rows[U_PER_BLOCK][D_DIM];   // 32 KB
    __shared__ float w_lds[NW_N];

    const int tid  = threadIdx.x;
    const int wave = tid >> 6;          // 0..7
    const int lane = tid & 63;
    const int u0   = blockIdx.x * U_PER_BLOCK;

    // Phase 0: zero rows (float4), stage w.
    {
        float4* r4 = (float4*)rows;
        const float4 z = make_float4(0.f, 0.f, 0.f, 0.f);
        #pragma unroll
        for (int i = tid; i < U_PER_BLOCK * D4; i += THREADS)
            r4[i] = z;
        if (tid < NW_N) w_lds[tid] = w[tid];
    }
    __syncthreads();

    // Phase 1: scatter. 256 (uu,k) pairs over 8 waves -> 32 pairs/wave.
    // No divisions: uu = pair>>6, k = pair&63. Lane sweeps the bucket.
    #pragma unroll 4
    for (int p = 0; p < 32; ++p) {
        const int pair = wave * 32 + p;           // 0..255
        const int uu   = pair >> 6;               // 0..3
        const int k    = pair & 63;               // 0..63
        const int* bp  = indices + ((size_t)(u0 + uu) * NW_N + k) * L;
        const float wk = w_lds[k];                // wave-uniform
        for (int l = lane; l < L; l += 64) {
            int idx = bp[l];
            if (idx > 0) rows[uu][idx - 1] = wk;
        }
    }
    __syncthreads();

    // Phase 2: each wave owns 8 batch rows; lanes split D as float4.
    const int b0 = wave * 8;                      // 8 waves x 8 = 64 rows
    const float4* x4 = (const float4*)x;

    float acc[8][U_PER_BLOCK];
    #pragma unroll
    for (int bj = 0; bj < 8; ++bj)
        #pragma unroll
        for (int uu = 0; uu < U_PER_BLOCK; ++uu)
            acc[bj][uu] = 0.0f;

    #pragma unroll 1   // keep live set ~90 VGPRs — full unroll spilled in R2
    for (int step = 0; step < D4 / 64; ++step) {  // 8 steps
        const int i4 = step * 64 + lane;          // 0..511
        float4 rv[U_PER_BLOCK];
        #pragma unroll
        for (int uu = 0; uu < U_PER_BLOCK; ++uu)
            rv[uu] = ((const float4*)rows[uu])[i4];   // ds_read_b128
        #pragma unroll
        for (int bj = 0; bj < 8; ++bj) {
            const float4 xv = x4[(b0 + bj) * D4 + i4];
            #pragma unroll
            for (int uu = 0; uu < U_PER_BLOCK; ++uu) {
                acc[bj][uu] += xv.x * rv[uu].x;
                acc[bj][uu] += xv.y * rv[uu].y;
                acc[bj][uu] += xv.z * rv[uu].z;
                acc[bj][uu] += xv.w * rv[uu].w;
            }
        }
    }

    // Phase 3: butterfly reduce, add bias, store (32 outputs/wave).
    #pragma unroll
    for (int bj = 0; bj < 8; ++bj) {
        #pragma unroll
        for (int uu = 0; uu < U_PER_BLOCK; ++uu) {
            float v = acc[bj][uu];
            #pragma unroll
            for (int off = 32; off > 0; off >>= 1)
                v += __shfl_down(v, off, 64);
            if (lane == 0)
                out[(b0 + bj) * UNITS_N + (u0 + uu)] = v + bias[u0 + uu];
        }
    }
}

extern "C" void kernel_launch(void* const* d_in, const int* in_sizes, int n_in,
                              void* d_out, int out_size, void* d_ws, size_t ws_size,
                              hipStream_t stream) {
    const float* x       = (const float*)d_in[0];
    const float* w       = (const float*)d_in[1];
    const float* bias    = (const float*)d_in[2];
    const int*   indices = (const int*)d_in[3];
    float*       out     = (float*)d_out;

    const int L = in_sizes[3] / (UNITS_N * NW_N);

    dim3 grid(UNITS_N / U_PER_BLOCK);   // 256 blocks = 1 per CU
    dim3 block(THREADS);                // 512 threads = 8 waves
    EfficientHashedLinear_72043781423546_kernel<<<grid, block, 0, stream>>>(
        x, w, bias, indices, out, L);
}

// Round 4
// 81.262 us; speedup vs baseline: 2.0399x; 1.2669x over previous
//
#include <hip/hip_runtime.h>

// B=64, D=2048, UNITS=1024, NW=64; L = in_sizes[3]/(UNITS*NW) (~56).
//
// out[b,u] = sum_i x[b,i] * W[u,i] + bias[u], W[u,i] = w[k] where bucket k of
// unit u contains position i (indices 1-shifted, 0 = pad). Buckets partition
// positions per unit -> LDS scatter builds W[u,:] race-free.
//
// R4 vs R3 post-mortem: R3 was latency-bound (VALUBusy 9%, HBM 2.5%, kernel
// 90% idle). Phase 1's per-pair runtime inner loop serialized 32 HBM-latency
// round-trips per wave. R4: (a) load-pass/scatter-pass split -> 16 independent
// index loads in flight per wave; (b) 1024 threads = 4 waves/SIMD for 2x TLP,
// __launch_bounds__(1024,4) caps VGPR at 128 (live set ~70, no spill -- R2's
// spill came from full unroll under a 64-VGPR cap, which we avoid).

#define B_DIM   64
#define D_DIM   2048
#define D4      (D_DIM / 4)     // 512 float4 per row
#define UNITS_N 1024
#define NW_N    64
#define U_PER_BLOCK 4
#define THREADS 1024
#define PAIRS_PER_WAVE 16       // 256 pairs / 16 waves

__global__ __launch_bounds__(THREADS, 4)
void EfficientHashedLinear_72043781423546_kernel(
    const float* __restrict__ x,        // (64, 2048)
    const float* __restrict__ w,        // (64,)
    const float* __restrict__ bias,     // (1024,)
    const int*   __restrict__ indices,  // (UNITS, NW, L) int32
    float*       __restrict__ out,      // (64, 1024)
    int L)
{
    __shared__ float rows[U_PER_BLOCK][D_DIM];   // 32 KB
    __shared__ float w_lds[NW_N];

    const int tid  = threadIdx.x;
    const int wave = tid >> 6;          // 0..15
    const int lane = tid & 63;
    const int u0   = blockIdx.x * U_PER_BLOCK;

    // Phase 0: zero rows (float4), stage w.
    {
        float4* r4 = (float4*)rows;
        const float4 z = make_float4(0.f, 0.f, 0.f, 0.f);
        #pragma unroll
        for (int i = tid; i < U_PER_BLOCK * D4; i += THREADS)
            r4[i] = z;
        if (tid < NW_N) w_lds[tid] = w[tid];
    }
    __syncthreads();

    // Phase 1a: load pass — 16 independent, lane-predicated loads per wave,
    // all in flight before any use (no dependent inner loops between them).
    int idxv[PAIRS_PER_WAVE];
    #pragma unroll
    for (int p = 0; p < PAIRS_PER_WAVE; ++p) {
        const int pair = wave * PAIRS_PER_WAVE + p;   // 0..255
        const int uu   = pair >> 6;                   // 0..3
        const int k    = pair & 63;                   // 0..63
        const int* bp  = indices + ((size_t)(u0 + uu) * NW_N + k) * L;
        idxv[p] = (lane < L) ? bp[lane] : 0;
    }
    // Phase 1b: scatter pass (LDS only).
    #pragma unroll
    for (int p = 0; p < PAIRS_PER_WAVE; ++p) {
        const int pair = wave * PAIRS_PER_WAVE + p;
        const int uu   = pair >> 6;
        const int k    = pair & 63;
        if (idxv[p] > 0) rows[uu][idxv[p] - 1] = w_lds[k];
    }
    // Generic tail for L > 64 (not expected with this data; kept for safety).
    if (L > 64) {
        #pragma unroll 1
        for (int p = 0; p < PAIRS_PER_WAVE; ++p) {
            const int pair = wave * PAIRS_PER_WAVE + p;
            const int uu   = pair >> 6;
            const int k    = pair & 63;
            const int* bp  = indices + ((size_t)(u0 + uu) * NW_N + k) * L;
            const float wk = w_lds[k];
            for (int l = 64 + lane; l < L; l += 64) {
                int idx = bp[l];
                if (idx > 0) rows[uu][idx - 1] = wk;
            }
        }
    }
    __syncthreads();

    // Phase 2: each wave owns 4 batch rows; lanes split D as float4.
    const int b0 = wave * 4;                      // 16 waves x 4 = 64 rows
    const float4* x4 = (const float4*)x;

    float acc[4][U_PER_BLOCK];
    #pragma unroll
    for (int bj = 0; bj < 4; ++bj)
        #pragma unroll
        for (int uu = 0; uu < U_PER_BLOCK; ++uu)
            acc[bj][uu] = 0.0f;

    #pragma unroll 1   // live set ~70 VGPRs; full unroll spilled in R2
    for (int step = 0; step < D4 / 64; ++step) {  // 8 steps
        const int i4 = step * 64 + lane;          // 0..511
        float4 rv[U_PER_BLOCK];
        #pragma unroll
        for (int uu = 0; uu < U_PER_BLOCK; ++uu)
            rv[uu] = ((const float4*)rows[uu])[i4];   // ds_read_b128
        #pragma unroll
        for (int bj = 0; bj < 4; ++bj) {
            const float4 xv = x4[(b0 + bj) * D4 + i4];
            #pragma unroll
            for (int uu = 0; uu < U_PER_BLOCK; ++uu) {
                acc[bj][uu] += xv.x * rv[uu].x;
                acc[bj][uu] += xv.y * rv[uu].y;
                acc[bj][uu] += xv.z * rv[uu].z;
                acc[bj][uu] += xv.w * rv[uu].w;
            }
        }
    }

    // Phase 3: butterfly reduce, add bias, store (16 outputs/wave).
    #pragma unroll
    for (int bj = 0; bj < 4; ++bj) {
        #pragma unroll
        for (int uu = 0; uu < U_PER_BLOCK; ++uu) {
            float v = acc[bj][uu];
            #pragma unroll
            for (int off = 32; off > 0; off >>= 1)
                v += __shfl_down(v, off, 64);
            if (lane == 0)
                out[(b0 + bj) * UNITS_N + (u0 + uu)] = v + bias[u0 + uu];
        }
    }
}

extern "C" void kernel_launch(void* const* d_in, const int* in_sizes, int n_in,
                              void* d_out, int out_size, void* d_ws, size_t ws_size,
                              hipStream_t stream) {
    const float* x       = (const float*)d_in[0];
    const float* w       = (const float*)d_in[1];
    const float* bias    = (const float*)d_in[2];
    const int*   indices = (const int*)d_in[3];
    float*       out     = (float*)d_out;

    const int L = in_sizes[3] / (UNITS_N * NW_N);

    dim3 grid(UNITS_N / U_PER_BLOCK);   // 256 blocks = 1 per CU
    dim3 block(THREADS);                // 1024 threads = 16 waves
    EfficientHashedLinear_72043781423546_kernel<<<grid, block, 0, stream>>>(
        x, w, bias, indices, out, L);
}